// Round 5
// baseline (46.608 us; speedup 1.0000x reference)
//
#include <hip/hip_runtime.h>

#define NPART  8192
#define NSPLIT 64                  // j-splits (ws = 64*8192*4 B = 2 MB, proven to fit)
#define JCHUNK (NPART / NSPLIT)    // 128 j's per block
#define RPT    4                   // i's per lane (register blocking)
#define IPW    (64 * RPT)          // 256 i's per wave
#define IPB    (IPW * 4)           // 1024 i's per block (4 waves)
#define ITILES (NPART / IPB)       // 8 i-tiles

// All-pairs partial-density kernel.
// Lanes own RPT i's in registers; j-tile staged in LDS and read as float4
// broadcasts (all 64 lanes same address -> conflict-free, 3 ds_read_b128 per
// 4-j group feeding 112 VALU ops). Per-lane accumulators only - no cross-lane
// ops anywhere in the loop (R4 lesson: readlane/shfl per iteration is poison).
//
// Cubic spline identity: w(q) = 2*max(1-q,0)^3 - max(1-2q,0)^3, q = 10 r
//   (== 1-6q^2+6q^3 for q<=0.5; 2(1-q)^3 for 0.5<q<=1; 0 for q>1).
// w == 0 exactly for d2 > 0.01, so one wave-uniform branch per group skips
// sqrt+poly for all 16 (r,j) pairs when nothing is inside the cutoff.
__global__ __launch_bounds__(256) void sph_pairs(const float* __restrict__ pos,
                                                 float* __restrict__ ws) {
    __shared__ float4 sj[JCHUNK * 3 / 4];   // 96 float4 = 1536 B

    const int tid  = threadIdx.x;
    const int lane = tid & 63;
    const int wv   = tid >> 6;
    const int bi   = blockIdx.x;            // i-tile  [0,8)
    const int bj   = blockIdx.y;            // j-split [0,64)

    // This lane's RPT i-positions (i = i0 + r*64), loaded before the barrier.
    const int i0 = bi * IPB + wv * IPW + lane;
    float ix[RPT], iy[RPT], iz[RPT];
#pragma unroll
    for (int r = 0; r < RPT; ++r) {
        const float* p = pos + 3 * (size_t)(i0 + r * 64);
        ix[r] = p[0]; iy[r] = p[1]; iz[r] = p[2];
    }

    // Stage j-tile (1536 B) with 96 float4 loads; byte offset 12*JCHUNK*bj
    // = 1536*bj is 16B-aligned.
    if (tid < JCHUNK * 3 / 4)
        sj[tid] = ((const float4*)(pos + (size_t)bj * JCHUNK * 3))[tid];
    __syncthreads();

    const float RCUT2 = 0.0100001f;   // (h=0.1)^2 + margin; w==0 beyond
    float acc1[RPT], acc2[RPT];
#pragma unroll
    for (int r = 0; r < RPT; ++r) { acc1[r] = 0.0f; acc2[r] = 0.0f; }

#pragma unroll 4
    for (int g = 0; g < JCHUNK / 4; ++g) {
        // 4 j-positions = 12 floats = 3 LDS float4 broadcasts
        const float4 p0 = sj[3 * g + 0];
        const float4 p1 = sj[3 * g + 1];
        const float4 p2 = sj[3 * g + 2];
        const float jx0 = p0.x, jy0 = p0.y, jz0 = p0.z;
        const float jx1 = p0.w, jy1 = p1.x, jz1 = p1.y;
        const float jx2 = p1.z, jy2 = p1.w, jz2 = p2.x;
        const float jx3 = p2.y, jy3 = p2.z, jz3 = p2.w;

        float d2[RPT][4];
#pragma unroll
        for (int r = 0; r < RPT; ++r) {
            const float dx0 = ix[r] - jx0, dy0 = iy[r] - jy0, dz0 = iz[r] - jz0;
            const float dx1 = ix[r] - jx1, dy1 = iy[r] - jy1, dz1 = iz[r] - jz1;
            const float dx2 = ix[r] - jx2, dy2 = iy[r] - jy2, dz2 = iz[r] - jz2;
            const float dx3 = ix[r] - jx3, dy3 = iy[r] - jy3, dz3 = iz[r] - jz3;
            d2[r][0] = fmaf(dx0, dx0, fmaf(dy0, dy0, fmaf(dz0, dz0, 1e-10f)));
            d2[r][1] = fmaf(dx1, dx1, fmaf(dy1, dy1, fmaf(dz1, dz1, 1e-10f)));
            d2[r][2] = fmaf(dx2, dx2, fmaf(dy2, dy2, fmaf(dz2, dz2, 1e-10f)));
            d2[r][3] = fmaf(dx3, dx3, fmaf(dy3, dy3, fmaf(dz3, dz3, 1e-10f)));
        }

        // Balanced min-tree over the 16 d2's (clang fuses fminf pairs to v_min3).
        float m0 = fminf(fminf(d2[0][0], d2[0][1]), fminf(d2[0][2], d2[0][3]));
        float m1 = fminf(fminf(d2[1][0], d2[1][1]), fminf(d2[1][2], d2[1][3]));
        float m2 = fminf(fminf(d2[2][0], d2[2][1]), fminf(d2[2][2], d2[2][3]));
        float m3 = fminf(fminf(d2[3][0], d2[3][1]), fminf(d2[3][2], d2[3][3]));
        const float m = fminf(fminf(m0, m1), fminf(m2, m3));

        if (__any(m <= RCUT2)) {
            // Rare path (~9% of groups): clamped cubics; far pairs give exact 0.
#pragma unroll
            for (int r = 0; r < RPT; ++r) {
#pragma unroll
                for (int c = 0; c < 4; ++c) {
                    const float rr = __builtin_amdgcn_sqrtf(d2[r][c]);
                    const float a  = fmaxf(fmaf(-10.0f, rr, 1.0f), 0.0f);
                    const float b  = fmaxf(fmaf(-20.0f, rr, 1.0f), 0.0f);
                    acc1[r] = fmaf(a * a, a, acc1[r]);
                    acc2[r] = fmaf(b * b, b, acc2[r]);
                }
            }
        }
    }

    // Four coalesced partial writes per wave.
#pragma unroll
    for (int r = 0; r < RPT; ++r)
        ws[(size_t)bj * NPART + i0 + r * 64] = fmaf(2.0f, acc1[r], -acc2[r]);
}

// Reduce the NSPLIT partials per particle (fixed order -> deterministic).
__global__ __launch_bounds__(256) void sph_reduce(const float* __restrict__ ws,
                                                  float* __restrict__ out) {
    const int i = blockIdx.x * 256 + threadIdx.x;
    float s = 0.0f;
#pragma unroll
    for (int k = 0; k < NSPLIT; ++k) s += ws[(size_t)k * NPART + i];
    // MASS * 8 / (PI * H^3), PI exactly as the reference literal
    const float norm = (float)(8.0 / (3.14159265 * 0.1 * 0.1 * 0.1));
    out[i] = s * norm;
}

extern "C" void kernel_launch(void* const* d_in, const int* in_sizes, int n_in,
                              void* d_out, int out_size, void* d_ws, size_t ws_size,
                              hipStream_t stream) {
    const float* pos = (const float*)d_in[0];
    float*       out = (float*)d_out;
    float*       ws  = (float*)d_ws;   // 2 MB of partials

    dim3 grid(ITILES, NSPLIT);         // 8 x 64 = 512 blocks
    sph_pairs<<<grid, 256, 0, stream>>>(pos, ws);
    sph_reduce<<<NPART / 256, 256, 0, stream>>>(ws, out);
}

// Round 6
// 29.188 us; speedup vs baseline: 1.5968x; 1.5968x over previous
//
#include <hip/hip_runtime.h>

#define NPART  8192
#define NSPLIT 64                  // j-splits
#define JCHUNK (NPART / NSPLIT)    // 128 j's per block
#define ITILES (NPART / 256)       // 32 i-tiles

typedef float f32x2 __attribute__((ext_vector_type(2)));

// Packed f32 add: s-operand is the wave-uniform j-pair (SGPRs), v-operand the
// negated per-lane i coordinate. One SGPR read per VALU instr (legal).
__device__ __forceinline__ f32x2 pk_add_sv(f32x2 s, f32x2 v) {
    f32x2 d;
    asm("v_pk_add_f32 %0, %1, %2" : "=v"(d) : "s"(s), "v"(v));
    return d;
}
__device__ __forceinline__ f32x2 pk_fma(f32x2 a, f32x2 b, f32x2 c) {
    f32x2 d;
    asm("v_pk_fma_f32 %0, %1, %2, %3" : "=v"(d) : "v"(a), "v"(b), "v"(c));
    return d;
}

// Pre-pass: AoS positions -> SoA (sx, sy, sz) so j-groups are contiguous
// 16B-aligned quads for scalar loads and packed math.
__global__ __launch_bounds__(256) void sph_prep(const float* __restrict__ pos,
                                                float* __restrict__ soa) {
    const int i = blockIdx.x * 256 + threadIdx.x;
    const float* p = pos + 3 * (size_t)i;
    soa[i]             = p[0];
    soa[i + NPART]     = p[1];
    soa[i + 2 * NPART] = p[2];
}

// All-pairs partial-density kernel. R2 mapping (1 i per lane, 2048 blocks =
// 8 waves/SIMD — occupancy is what R4/R5 proved matters), but:
//  - j-data fetched via the SCALAR pipe (uniform address -> s_load_dwordx4),
//    no LDS, no barriers;
//  - distance math in packed f32 (VOP3P), 2 pairs per instruction.
// Cubic spline identity: w(q) = 2*max(1-q,0)^3 - max(1-2q,0)^3, q = 10 r;
// w == 0 exactly for d2 > 0.01 -> wave-uniform early exit per 4-j group.
__global__ __launch_bounds__(256) void sph_pairs(const float* __restrict__ pos,
                                                 const float* __restrict__ soa,
                                                 float* __restrict__ ws) {
    const int tid = threadIdx.x;
    const int i   = blockIdx.x * 256 + tid;
    const int j0  = blockIdx.y * JCHUNK;

    const float* sx = soa;
    const float* sy = soa + NPART;
    const float* sz = soa + 2 * NPART;

    const float* p = pos + 3 * (size_t)i;
    const float xi = p[0], yi = p[1], zi = p[2];
    const f32x2 nix = {-xi, -xi}, niy = {-yi, -yi}, niz = {-zi, -zi};
    const f32x2 eps2 = {1e-10f, 1e-10f};

    const float RCUT2 = 0.0100001f;   // (h=0.1)^2 + margin; w==0 beyond
    float acc1 = 0.0f, acc2 = 0.0f;

#pragma unroll 2
    for (int j = j0; j < j0 + JCHUNK; j += 4) {
        // 3 uniform 16B loads -> SGPR quads (scalar cache), no VALU/LDS cost.
        const float4 xq = *(const float4*)&sx[j];
        const float4 yq = *(const float4*)&sy[j];
        const float4 zq = *(const float4*)&sz[j];

        const f32x2 dx01 = pk_add_sv((f32x2){xq.x, xq.y}, nix);
        const f32x2 dx23 = pk_add_sv((f32x2){xq.z, xq.w}, nix);
        const f32x2 dy01 = pk_add_sv((f32x2){yq.x, yq.y}, niy);
        const f32x2 dy23 = pk_add_sv((f32x2){yq.z, yq.w}, niy);
        const f32x2 dz01 = pk_add_sv((f32x2){zq.x, zq.y}, niz);
        const f32x2 dz23 = pk_add_sv((f32x2){zq.z, zq.w}, niz);

        // d2 = dx^2 + dy^2 + dz^2 + eps, eps innermost (same order as R2).
        f32x2 a01 = pk_fma(dz01, dz01, eps2);
        a01 = pk_fma(dy01, dy01, a01);
        a01 = pk_fma(dx01, dx01, a01);
        f32x2 a23 = pk_fma(dz23, dz23, eps2);
        a23 = pk_fma(dy23, dy23, a23);
        a23 = pk_fma(dx23, dx23, a23);

        const float m = fminf(fminf(a01.x, a01.y), fminf(a23.x, a23.y));
        if (__any(m <= RCUT2)) {
            // Rare path: clamped cubics; far pairs contribute exactly 0.
            const float d20 = a01.x, d21 = a01.y, d22 = a23.x, d23 = a23.y;
            {
                const float r = __builtin_amdgcn_sqrtf(d20);
                const float a = fmaxf(fmaf(-10.0f, r, 1.0f), 0.0f);
                const float b = fmaxf(fmaf(-20.0f, r, 1.0f), 0.0f);
                acc1 = fmaf(a * a, a, acc1);
                acc2 = fmaf(b * b, b, acc2);
            }
            {
                const float r = __builtin_amdgcn_sqrtf(d21);
                const float a = fmaxf(fmaf(-10.0f, r, 1.0f), 0.0f);
                const float b = fmaxf(fmaf(-20.0f, r, 1.0f), 0.0f);
                acc1 = fmaf(a * a, a, acc1);
                acc2 = fmaf(b * b, b, acc2);
            }
            {
                const float r = __builtin_amdgcn_sqrtf(d22);
                const float a = fmaxf(fmaf(-10.0f, r, 1.0f), 0.0f);
                const float b = fmaxf(fmaf(-20.0f, r, 1.0f), 0.0f);
                acc1 = fmaf(a * a, a, acc1);
                acc2 = fmaf(b * b, b, acc2);
            }
            {
                const float r = __builtin_amdgcn_sqrtf(d23);
                const float a = fmaxf(fmaf(-10.0f, r, 1.0f), 0.0f);
                const float b = fmaxf(fmaf(-20.0f, r, 1.0f), 0.0f);
                acc1 = fmaf(a * a, a, acc1);
                acc2 = fmaf(b * b, b, acc2);
            }
        }
    }

    ws[(size_t)blockIdx.y * NPART + i] = fmaf(2.0f, acc1, -acc2);
}

// Reduce NSPLIT partials per particle (fixed order -> deterministic) + scale.
__global__ __launch_bounds__(256) void sph_reduce(const float* __restrict__ part,
                                                  float* __restrict__ out) {
    const int i = blockIdx.x * 256 + threadIdx.x;
    float s = 0.0f;
#pragma unroll
    for (int k = 0; k < NSPLIT; ++k) s += part[(size_t)k * NPART + i];
    // MASS * 8 / (PI * H^3), PI exactly as the reference literal
    const float norm = (float)(8.0 / (3.14159265 * 0.1 * 0.1 * 0.1));
    out[i] = s * norm;
}

extern "C" void kernel_launch(void* const* d_in, const int* in_sizes, int n_in,
                              void* d_out, int out_size, void* d_ws, size_t ws_size,
                              hipStream_t stream) {
    const float* pos  = (const float*)d_in[0];
    float*       out  = (float*)d_out;
    float*       soa  = (float*)d_ws;                    // 3 * 8192 floats
    float*       part = soa + 3 * (size_t)NPART;         // 64 * 8192 floats

    sph_prep<<<ITILES, 256, 0, stream>>>(pos, soa);
    dim3 grid(ITILES, NSPLIT);                           // 2048 blocks
    sph_pairs<<<grid, 256, 0, stream>>>(pos, soa, part);
    sph_reduce<<<ITILES, 256, 0, stream>>>(part, out);
}

// Round 7
// 25.034 us; speedup vs baseline: 1.8618x; 1.1660x over previous
//
#include <hip/hip_runtime.h>

#define NPART  8192
#define NSPLIT 64                  // j-splits
#define JCHUNK (NPART / NSPLIT)    // 128 j's per block
#define ITILES (NPART / 256)       // 32 i-tiles

typedef float f32x2 __attribute__((ext_vector_type(2)));

// Packed f32 (VOP3P, full-rate dual f32 per instruction on CDNA).
__device__ __forceinline__ f32x2 pk_add(f32x2 a, f32x2 b) {
    f32x2 d;
    asm("v_pk_add_f32 %0, %1, %2" : "=v"(d) : "v"(a), "v"(b));
    return d;
}
__device__ __forceinline__ f32x2 pk_fma(f32x2 a, f32x2 b, f32x2 c) {
    f32x2 d;
    asm("v_pk_fma_f32 %0, %1, %2, %3" : "=v"(d) : "v"(a), "v"(b), "v"(c));
    return d;
}

// All-pairs partial-density kernel — R2's proven structure (1 i per lane,
// LDS-staged j-tile, 2048 blocks = 8 blocks/CU = full 32 waves/CU) with the
// VALU stream halved via packed f32. The j-tile is staged in LDS as SoA
// (x[128] | y[128] | z[128]) so each ds_read_b128 broadcast yields quads
// whose (0,1) and (2,3) subpairs feed v_pk_* operands with zero v_movs.
//
// Cubic spline identity: w(q) = 2*max(1-q,0)^3 - max(1-2q,0)^3, q = 10 r
//   (== 1-6q^2+6q^3 for q<=0.5; 2(1-q)^3 for 0.5<q<=1; 0 for q>1).
// w == 0 exactly for d2 > 0.01 -> one wave-uniform branch per 4-j group
// skips sqrt+poly (hit rate ~2.4%). FP order identical to R2 (absmax 0).
__global__ __launch_bounds__(256) void sph_pairs(const float* __restrict__ pos,
                                                 float* __restrict__ ws) {
    __shared__ float slds[3 * JCHUNK];   // x[128] | y[128] | z[128], 1536 B

    const int tid = threadIdx.x;
    const int i   = blockIdx.x * 256 + tid;
    const int bj  = blockIdx.y;

    // Stage j-tile AoS->SoA: scalar coalesced loads, scattered LDS writes
    // (one-time; 384 elements, tid<128 does 3 each... strided loop).
    {
        const float* src = pos + (size_t)bj * JCHUNK * 3;
        for (int s = tid; s < 3 * JCHUNK; s += 256)
            slds[(s % 3) * JCHUNK + s / 3] = src[s];
    }
    __syncthreads();

    const float* p = pos + 3 * (size_t)i;
    const float xi = p[0], yi = p[1], zi = p[2];
    const f32x2 nix = {-xi, -xi}, niy = {-yi, -yi}, niz = {-zi, -zi};
    const f32x2 eps2 = {1e-10f, 1e-10f};

    const float RCUT2 = 0.0100001f;   // (h=0.1)^2 + margin; w==0 beyond
    float acc1 = 0.0f, acc2 = 0.0f;

#pragma unroll 2
    for (int g = 0; g < JCHUNK / 4; ++g) {
        // 3 ds_read_b128 broadcasts (uniform address -> conflict-free).
        const float4 xq = *(const float4*)&slds[4 * g];
        const float4 yq = *(const float4*)&slds[JCHUNK + 4 * g];
        const float4 zq = *(const float4*)&slds[2 * JCHUNK + 4 * g];

        // (j - i) pairs; sign irrelevant (squared next).
        const f32x2 dx01 = pk_add((f32x2){xq.x, xq.y}, nix);
        const f32x2 dx23 = pk_add((f32x2){xq.z, xq.w}, nix);
        const f32x2 dy01 = pk_add((f32x2){yq.x, yq.y}, niy);
        const f32x2 dy23 = pk_add((f32x2){yq.z, yq.w}, niy);
        const f32x2 dz01 = pk_add((f32x2){zq.x, zq.y}, niz);
        const f32x2 dz23 = pk_add((f32x2){zq.z, zq.w}, niz);

        // d2 = dx^2 + dy^2 + dz^2 + eps, eps innermost (same order as R2).
        f32x2 a01 = pk_fma(dz01, dz01, eps2);
        a01 = pk_fma(dy01, dy01, a01);
        a01 = pk_fma(dx01, dx01, a01);
        f32x2 a23 = pk_fma(dz23, dz23, eps2);
        a23 = pk_fma(dy23, dy23, a23);
        a23 = pk_fma(dx23, dx23, a23);

        const float m = fminf(fminf(a01.x, a01.y), fminf(a23.x, a23.y));
        if (__any(m <= RCUT2)) {
            // Rare path: clamped cubics; far pairs contribute exactly 0.
            const float d2v[4] = {a01.x, a01.y, a23.x, a23.y};
#pragma unroll
            for (int c = 0; c < 4; ++c) {
                const float r = __builtin_amdgcn_sqrtf(d2v[c]);
                const float a = fmaxf(fmaf(-10.0f, r, 1.0f), 0.0f);
                const float b = fmaxf(fmaf(-20.0f, r, 1.0f), 0.0f);
                acc1 = fmaf(a * a, a, acc1);
                acc2 = fmaf(b * b, b, acc2);
            }
        }
    }

    ws[(size_t)bj * NPART + i] = fmaf(2.0f, acc1, -acc2);
}

// Reduce NSPLIT partials per particle (fixed order -> deterministic) + scale.
// Fully unrolled: 64 independent coalesced loads in flight -> ~one latency.
__global__ __launch_bounds__(256) void sph_reduce(const float* __restrict__ part,
                                                  float* __restrict__ out) {
    const int i = blockIdx.x * 256 + threadIdx.x;
    float s = 0.0f;
#pragma unroll
    for (int k = 0; k < NSPLIT; ++k) s += part[(size_t)k * NPART + i];
    // MASS * 8 / (PI * H^3), PI exactly as the reference literal
    const float norm = (float)(8.0 / (3.14159265 * 0.1 * 0.1 * 0.1));
    out[i] = s * norm;
}

extern "C" void kernel_launch(void* const* d_in, const int* in_sizes, int n_in,
                              void* d_out, int out_size, void* d_ws, size_t ws_size,
                              hipStream_t stream) {
    const float* pos  = (const float*)d_in[0];
    float*       out  = (float*)d_out;
    float*       part = (float*)d_ws;    // 64 * 8192 * 4 B = 2 MB

    dim3 grid(ITILES, NSPLIT);           // 2048 blocks, 8 blocks/CU
    sph_pairs<<<grid, 256, 0, stream>>>(pos, part);
    sph_reduce<<<ITILES, 256, 0, stream>>>(part, out);
}